// Round 10
// baseline (172.768 us; speedup 1.0000x reference)
//
#include <hip/hip_runtime.h>

using bf16   = __bf16;
using bf16x4 = __bf16 __attribute__((ext_vector_type(4)));
using bf16x8 = __bf16 __attribute__((ext_vector_type(8)));
using f32x4  = float __attribute__((ext_vector_type(4)));
using f32x16 = float __attribute__((ext_vector_type(16)));
using u32x2  = unsigned int __attribute__((ext_vector_type(2)));
using u32x4  = unsigned int __attribute__((ext_vector_type(4)));

#define L_SEQ  2048
#define DMODEL 2048
#define NQH    32
#define NKVH   8
#define HDIM   64
#define QKV_N  3072   // NQH*HDIM + 2*NKVH*HDIM

// fragment-ordered K/V: per kv-head, 64 key-blocks of 32; each block = 4 frags
// of (64 lanes x 8 elems) = 2048 elems; per-head stride:
#define KVF_HSTRIDE (64 * 4 * 64 * 8)   // 131072 elems = 256 KiB

// ---------- helpers ----------
__device__ __forceinline__ void gload_lds16(const void* g, void* lds) {
  __builtin_amdgcn_global_load_lds((__attribute__((address_space(1))) void*)(g),
                                   (__attribute__((address_space(3))) void*)(lds),
                                   16, 0, 0);
}

__device__ __forceinline__ unsigned pack2(float a, float b) {
  union { bf16 h[2]; unsigned u; } x;
  x.h[0] = (bf16)a; x.h[1] = (bf16)b;
  return x.u;
}

// assemble the PV B-fragment from 8 per-lane P values (swapped layout)
__device__ __forceinline__ bf16x8 make_pfrag(float p0, float p1, float p2, float p3,
                                             float p4, float p5, float p6, float p7,
                                             int hi) {
  const unsigned W0 = pack2(p0, p1);
  const unsigned W1 = pack2(p2, p3);
  const unsigned W2 = pack2(p4, p5);
  const unsigned W3 = pack2(p6, p7);
  u32x4 pw;
#if __has_builtin(__builtin_amdgcn_permlane32_swap)
  {
    using i32x2 = int __attribute__((ext_vector_type(2)));
    const i32x2 r02 = __builtin_amdgcn_permlane32_swap((int)W0, (int)W2, false, false);
    const i32x2 r13 = __builtin_amdgcn_permlane32_swap((int)W1, (int)W3, false, false);
    pw = u32x4{ (unsigned)r02[0], (unsigned)r13[0], (unsigned)r02[1], (unsigned)r13[1] };
  }
#else
  {
    const unsigned X0 = (unsigned)__shfl_xor((int)W0, 32);
    const unsigned X1 = (unsigned)__shfl_xor((int)W1, 32);
    const unsigned X2 = (unsigned)__shfl_xor((int)W2, 32);
    const unsigned X3 = (unsigned)__shfl_xor((int)W3, 32);
    pw = u32x4{ hi ? X2 : W0, hi ? X3 : W1, hi ? W2 : X0, hi ? W3 : X1 };
  }
#endif
  return __builtin_bit_cast(bf16x8, pw);
}

// cumulative chunk count before qi (chunks of 16 subtiles)
__device__ __forceinline__ int chunk_base(int qi) {
  return (qi < 16) ? qi
       : (qi < 32) ? 16 + 2 * (qi - 16)
       : (qi < 48) ? 48 + 3 * (qi - 32)
                   : 96 + 4 * (qi - 48);
}

// ---------- fused fp32 -> bf16 convert (x, w_qkv, w_out in one launch) ----------
#define N4_X  (L_SEQ * DMODEL / 4)          // 1048576
#define N4_WQ (QKV_N * DMODEL / 4)          // 1572864
#define N4_WO (DMODEL * DMODEL / 4)         // 1048576
__global__ void cvt3_f32_bf16(const float* __restrict__ x, const float* __restrict__ wq,
                              const float* __restrict__ wo, bf16* __restrict__ xb,
                              bf16* __restrict__ wqb, bf16* __restrict__ wob) {
  const long stride = (long)gridDim.x * blockDim.x;
  const long ntot = N4_X + N4_WQ + N4_WO;
  for (long i = (long)blockIdx.x * blockDim.x + threadIdx.x; i < ntot; i += stride) {
    const float* src; bf16* dst; long j;
    if (i < N4_X)               { src = x;  dst = xb;  j = i; }
    else if (i < N4_X + N4_WQ)  { src = wq; dst = wqb; j = i - N4_X; }
    else                        { src = wo; dst = wob; j = i - N4_X - N4_WQ; }
    const float4 v = reinterpret_cast<const float4*>(src)[j];
    bf16x4 o = { (bf16)v.x, (bf16)v.y, (bf16)v.z, (bf16)v.w };
    reinterpret_cast<bf16x4*>(dst)[j] = o;
  }
}

// ---------- bf16 GEMM: C(MxN) = A(MxK) * B(NxK)^T, 128x64 tile, BK=64 ----------
// 2 waves per block; each wave computes the FULL 64x64 half-tile.
// Split-K via gridDim.z: block z covers K-range [z*K/gz, (z+1)*K/gz), writing
// its partial to C + z*M*N. gz=1 -> plain GEMM.
template <typename OutT>
__global__ __launch_bounds__(128)
void gemm_bt(const bf16* __restrict__ A, const bf16* __restrict__ B,
             OutT* __restrict__ C, int M, int N, int K) {
  __shared__ bf16 As[128 * 64];
  __shared__ bf16 Bs[64 * 64];
  const int tid = threadIdx.x;
  const int w = tid >> 6, l = tid & 63;
  const int lq = l & 15, lg = l >> 4;
  const long m0 = (long)blockIdx.y * 128;
  const long n0 = (long)blockIdx.x * 64;
  const int ks = K / gridDim.z;
  const int kb = blockIdx.z * ks;
  C += (long)blockIdx.z * M * N;

  const int lrow = l >> 3;                   // row within 8-row group (0..7)
  const int scol = ((l & 7) ^ lrow) << 3;    // pre-swizzled global element column

  f32x4 acc[4][4];
#pragma unroll
  for (int i = 0; i < 4; ++i)
#pragma unroll
    for (int j = 0; j < 4; ++j) acc[i][j] = f32x4{0.f, 0.f, 0.f, 0.f};

  for (int k0 = kb; k0 < kb + ks; k0 += 64) {
#pragma unroll
    for (int i = 0; i < 8; ++i) {
      const int r0 = (i * 2 + w) * 8;
      gload_lds16(A + (m0 + r0 + lrow) * (long)K + k0 + scol, &As[r0 * 64]);
    }
#pragma unroll
    for (int i = 0; i < 4; ++i) {
      const int r0 = (i * 2 + w) * 8;
      gload_lds16(B + (n0 + r0 + lrow) * (long)K + k0 + scol, &Bs[r0 * 64]);
    }
    __syncthreads();
#pragma unroll
    for (int kk = 0; kk < 2; ++kk) {
      bf16x8 af[4], bfr[4];
#pragma unroll
      for (int t = 0; t < 4; ++t) {
        const int rowA = w * 64 + t * 16 + lq;
        const int blkA = (kk * 4 + lg) ^ (rowA & 7);
        af[t] = *reinterpret_cast<const bf16x8*>(&As[rowA * 64 + blkA * 8]);
        const int rowB = t * 16 + lq;
        const int blkB = (kk * 4 + lg) ^ (rowB & 7);
        bfr[t] = *reinterpret_cast<const bf16x8*>(&Bs[rowB * 64 + blkB * 8]);
      }
#pragma unroll
      for (int mt = 0; mt < 4; ++mt)
#pragma unroll
        for (int nt = 0; nt < 4; ++nt)
          acc[mt][nt] = __builtin_amdgcn_mfma_f32_16x16x32_bf16(af[mt], bfr[nt], acc[mt][nt], 0, 0, 0);
    }
    __syncthreads();
  }

#pragma unroll
  for (int mt = 0; mt < 4; ++mt)
#pragma unroll
    for (int r = 0; r < 4; ++r) {
      const long row = m0 + w * 64 + mt * 16 + lg * 4 + r;
#pragma unroll
      for (int nt = 0; nt < 4; ++nt) {
        const long col = n0 + nt * 16 + lq;
        C[row * (long)N + col] = (OutT)acc[mt][nt][r];
      }
    }
}

// ---------- RoPE + RMSNorm for Q and K (reads 2 split-K partials, adds) ----------
// Q scaled by SCALE*log2(e); K written directly in MFMA-fragment order.
__global__ __launch_bounds__(256)
void rope_rms(const bf16* __restrict__ pA, const bf16* __restrict__ pB,
              const float* __restrict__ qg, const float* __restrict__ kg,
              bf16* __restrict__ qo, bf16* __restrict__ kfr) {
  const int gid = blockIdx.x * 4 + (threadIdx.x >> 6);
  const int lane = threadIdx.x & 63;
  const int pos = gid / 40;
  const int hh = gid % 40;            // 0..31 q heads, 32..39 k heads
  const bool isq = hh < 32;
  const int col = isq ? hh * HDIM : NQH * HDIM + (hh - 32) * HDIM;

  const long idx = (long)pos * QKV_N + col + lane;
  float x = (float)pA[idx] + (float)pB[idx];
  float p = __shfl_xor(x, 1);
  const float fi = (float)(lane & ~1) * (1.0f / 64.0f);
  const float inv = powf(50000.0f, -fi);
  const float ang = (float)pos * inv;
  const float sn = sinf(ang), cs = cosf(ang);
  const float r = (lane & 1) ? (p * sn + x * cs) : (x * cs - p * sn);

  float ss = r * r;
#pragma unroll
  for (int off = 1; off < 64; off <<= 1) ss += __shfl_xor(ss, off);
  const float scl = rsqrtf(ss * (1.0f / 64.0f) + 1e-5f);
  const float g = isq ? qg[lane] : kg[lane];
  const float o = r * scl * g;

  if (isq) {
    qo[(long)pos * DMODEL + hh * HDIM + lane] = (bf16)(o * 0.18033688011112042f);
  } else {
    const int kvh = hh - 32;
    const int d = lane;
    const int lp = (pos & 31) + (((d >> 3) & 1) << 5);
    const long kidx = ((((long)kvh * 64 + (pos >> 5)) * 4 + (d >> 4)) * 64 + lp) * 8 + (d & 7);
    kfr[kidx] = (bf16)o;
  }
}

// ---------- V repack (reads 2 split-K partials): -> vfr MFMA-fragment order ----------
__global__ __launch_bounds__(256)
void repack_v(const bf16* __restrict__ pA, const bf16* __restrict__ pB,
              bf16* __restrict__ vfr) {
  __shared__ bf16 t[32][72];
  const int kvh = blockIdx.x >> 6;
  const int kb = blockIdx.x & 63;
  const int tid = threadIdx.x;

  {
    const int row = tid >> 3;
    const int cc = (tid & 7) * 8;
    const long goff = (long)(kb * 32 + row) * QKV_N + (NQH * HDIM + NKVH * HDIM) + kvh * HDIM + cc;
    const bf16x8 a = *reinterpret_cast<const bf16x8*>(pA + goff);
    const bf16x8 b = *reinterpret_cast<const bf16x8*>(pB + goff);
    bf16x8 s;
#pragma unroll
    for (int e = 0; e < 8; ++e) s[e] = (bf16)((float)a[e] + (float)b[e]);
    *reinterpret_cast<bf16x8*>(&t[row][cc]) = s;
  }
  __syncthreads();

  const int f = tid >> 6, l = tid & 63;
  const int s = f >> 1, dh = f & 1;
  const int hi = l >> 5, l31 = l & 31;
  union { bf16 b[8]; u32x4 u; } o;
#pragma unroll
  for (int e = 0; e < 8; ++e) o.b[e] = t[s * 16 + hi * 8 + e][dh * 32 + l31];
  bf16* od = vfr + (((long)(kvh * 64 + kb) * 4 + f) * 64 + l) * 8;
  *reinterpret_cast<u32x4*>(od) = o.u;
}

// ---------- flash attention (causal, GQA), fine split-K, XCD-pinned ----------
// 1280 blocks; kvh = blockIdx%8 pins K/V to one XCD's L2. The 4 waves of a
// block process the SAME (qi, chunk) for the 4 q-heads of the kv-head, and
// K/V subtiles are staged to LDS ONCE per block (double-buffered,
// stage(t+1)-before-compute(t), one barrier/iter) -- 4x VMEM dedup and the
// load latency hides under a full subtile of compute.
__global__ __launch_bounds__(256)
void flash_attn(const bf16* __restrict__ Q, const bf16* __restrict__ Kfr,
                const bf16* __restrict__ Vfr,
                bf16* __restrict__ po, float* __restrict__ pm, float* __restrict__ pl) {
  __shared__ bf16 Ks[2][2048];
  __shared__ bf16 Vs[2][2048];
  const int tid = threadIdx.x;
  const int w = tid >> 6, l = tid & 63;
  const int lane31 = l & 31, hi = l >> 5;
  const int bb = blockIdx.x;
  const int kvh = bb & 7;               // XCD pin
  const int g = bb >> 3;                // 0..159 chunk id within kv-head

  // invert cumulative chunk id -> (qi, c)
  int qi, c;
  if (g < 16)      { qi = g;                  c = 0; }
  else if (g < 48) { qi = 16 + ((g - 16) >> 1); c = (g - 16) & 1; }
  else if (g < 96) { qi = 32 + (g - 48) / 3;    c = (g - 48) % 3; }
  else             { qi = 48 + ((g - 96) >> 2); c = (g - 96) & 3; }

  const int h = kvh * 4 + w;            // wave -> q-head
  const int s0 = c * 16;
  const int s1 = min(qi + 1, s0 + 16);
  const int pidx = h * 160 + g;         // g == chunk_base(qi) + c

  const int q0 = qi * 32;
  const int q_abs = q0 + lane31;
  const int l8 = l * 8;

  const bf16* kfrh = Kfr + (long)kvh * KVF_HSTRIDE;
  const bf16* vfrh = Vfr + (long)kvh * KVF_HSTRIDE;

  // Q fragments (B-frag of ST): lane -> Q[q0+lane31][cc*16 + hi*8 + e]
  const bf16* qrow = Q + (long)q_abs * DMODEL + h * HDIM + hi * 8;
  bf16x8 qf[4];
#pragma unroll
  for (int cc = 0; cc < 4; ++cc) qf[cc] = *reinterpret_cast<const bf16x8*>(qrow + cc * 16);

  f32x16 o0, o1;
#pragma unroll
  for (int r = 0; r < 16; ++r) { o0[r] = 0.f; o1[r] = 0.f; }
  float m = -3.0e38f, lsum = 0.f;

  // prologue: stage subtile s0 into buf 0 (8 KB, 2 x 16B per thread)
  gload_lds16(kfrh + (long)s0 * 2048 + tid * 8, &Ks[0][tid * 8]);
  gload_lds16(vfrh + (long)s0 * 2048 + tid * 8, &Vs[0][tid * 8]);
  __syncthreads();

  int buf = 0;
  for (int sti = s0; sti < s1; ++sti) {
    const int kb0 = sti * 32;

    // stage NEXT subtile into the other buffer (in flight across compute)
    if (sti + 1 < s1) {
      gload_lds16(kfrh + (long)(sti + 1) * 2048 + tid * 8, &Ks[buf ^ 1][tid * 8]);
      gload_lds16(vfrh + (long)(sti + 1) * 2048 + tid * 8, &Vs[buf ^ 1][tid * 8]);
    }

    // ---- ST = K * Q^T over 4 d-chunks (K frags from LDS, lane-linear) ----
    const bf16x8 kc0 = *reinterpret_cast<const bf16x8*>(&Ks[buf][l8]);
    const bf16x8 kc1 = *reinterpret_cast<const bf16x8*>(&Ks[buf][512 + l8]);
    const bf16x8 kc2 = *reinterpret_cast<const bf16x8*>(&Ks[buf][1024 + l8]);
    const bf16x8 kc3 = *reinterpret_cast<const bf16x8*>(&Ks[buf][1536 + l8]);
    f32x16 st;
#pragma unroll
    for (int r = 0; r < 16; ++r) st[r] = 0.f;
    st = __builtin_amdgcn_mfma_f32_32x32x16_bf16(kc0, qf[0], st, 0, 0, 0);
    st = __builtin_amdgcn_mfma_f32_32x32x16_bf16(kc1, qf[1], st, 0, 0, 0);
    st = __builtin_amdgcn_mfma_f32_32x32x16_bf16(kc2, qf[2], st, 0, 0, 0);
    st = __builtin_amdgcn_mfma_f32_32x32x16_bf16(kc3, qf[3], st, 0, 0, 0);

    // V fragments (LDS reads issue early; consumed after softmax)
    const bf16x8 va0 = *reinterpret_cast<const bf16x8*>(&Vs[buf][l8]);
    const bf16x8 vb0 = *reinterpret_cast<const bf16x8*>(&Vs[buf][512 + l8]);
    const bf16x8 va1 = *reinterpret_cast<const bf16x8*>(&Vs[buf][1024 + l8]);
    const bf16x8 vb1 = *reinterpret_cast<const bf16x8*>(&Vs[buf][1536 + l8]);

    // ---- causal mask (diagonal subtile only) ----
    if (kb0 + 31 > q0) {
#pragma unroll
      for (int r = 0; r < 16; ++r) {
        const int k_abs = kb0 + (r & 3) + 8 * (r >> 2) + 4 * hi;
        if (k_abs > q_abs) st[r] = -3.0e38f;
      }
    }

    // ---- online softmax (base-2 domain; scale folded into Q) ----
    float t[8];
#pragma unroll
    for (int r = 0; r < 8; ++r) t[r] = fmaxf(st[r], st[r + 8]);
#pragma unroll
    for (int s = 4; s > 0; s >>= 1)
#pragma unroll
      for (int r = 0; r < 4; ++r) if (r < s) t[r] = fmaxf(t[r], t[r + s]);
    float mx = fmaxf(t[0], __shfl_xor(t[0], 32));

    if (!__all(mx - m <= 8.0f)) {        // defer-max, THR=8
      const float mn = fmaxf(m, mx);
      const float al = __builtin_amdgcn_exp2f(m - mn);
      m = mn; lsum *= al;
#pragma unroll
      for (int r = 0; r < 16; ++r) { o0[r] *= al; o1[r] *= al; }
    }
    float rs = 0.f;
#pragma unroll
    for (int r = 0; r < 16; ++r) { st[r] = __builtin_amdgcn_exp2f(st[r] - m); rs += st[r]; }
    rs += __shfl_xor(rs, 32);
    lsum += rs;

    // ---- PV: assemble P B-frags in-register, 2 k-slices ----
    {
      const bf16x8 pf0 = make_pfrag(st[0], st[1], st[2], st[3], st[4], st[5], st[6], st[7], hi);
      o0 = __builtin_amdgcn_mfma_f32_32x32x16_bf16(va0, pf0, o0, 0, 0, 0);
      o1 = __builtin_amdgcn_mfma_f32_32x32x16_bf16(vb0, pf0, o1, 0, 0, 0);
      const bf16x8 pf1 = make_pfrag(st[8], st[9], st[10], st[11], st[12], st[13], st[14], st[15], hi);
      o0 = __builtin_amdgcn_mfma_f32_32x32x16_bf16(va1, pf1, o0, 0, 0, 0);
      o1 = __builtin_amdgcn_mfma_f32_32x32x16_bf16(vb1, pf1, o1, 0, 0, 0);
    }

    __syncthreads();                     // drains next-tile stage, frees buf
    buf ^= 1;
  }

  // ---- store bf16 partial (unnormalized) + f32 stats ----
  bf16* pbase = po + (long)pidx * 2048 + lane31 * 64;
#pragma unroll
  for (int gg = 0; gg < 4; ++gg) {
    const int d0 = 8 * gg + 4 * hi;
    u32x2 s0v = { pack2(o0[4 * gg + 0], o0[4 * gg + 1]),
                  pack2(o0[4 * gg + 2], o0[4 * gg + 3]) };
    u32x2 s1v = { pack2(o1[4 * gg + 0], o1[4 * gg + 1]),
                  pack2(o1[4 * gg + 2], o1[4 * gg + 3]) };
    *reinterpret_cast<u32x2*>(pbase + d0) = s0v;
    *reinterpret_cast<u32x2*>(pbase + 32 + d0) = s1v;
  }
  if (hi == 0) {
    pm[pidx * 32 + lane31] = m;
    pl[pidx * 32 + lane31] = lsum;
  }
}

// ---------- combine partials: ao[q] = Σ_c O_c·2^(m_c−M) / Σ_c l_c·2^(m_c−M) ----------
__global__ __launch_bounds__(256)
void combine_split(const bf16* __restrict__ po, const float* __restrict__ pm,
                   const float* __restrict__ pl, bf16* __restrict__ ao) {
  const int t = blockIdx.x * 2 + (threadIdx.x >> 7);
  const int tid7 = threadIdx.x & 127;
  const int r = tid7 >> 2;                 // q row 0..31
  const int dc = (tid7 & 3) * 16;          // d chunk
  const int h = t >> 6, qi = t & 63;
  const int nc = 1 + (qi >> 4);
  const int p0 = h * 160 + chunk_base(qi);

  float mv0 = -3e38f, mv1 = -3e38f, mv2 = -3e38f, mv3 = -3e38f;
  float lv0 = 0.f, lv1 = 0.f, lv2 = 0.f, lv3 = 0.f;
  mv0 = pm[(p0 + 0) * 32 + r];              lv0 = pl[(p0 + 0) * 32 + r];
  if (nc > 1) { mv1 = pm[(p0 + 1) * 32 + r]; lv1 = pl[(p0 + 1) * 32 + r]; }
  if (nc > 2) { mv2 = pm[(p0 + 2) * 32 + r]; lv2 = pl[(p0 + 2) * 32 + r]; }
  if (nc > 3) { mv3 = pm[(p0 + 3) * 32 + r]; lv3 = pl[(p0 + 3) * 32 + r]; }
  const float M = fmaxf(fmaxf(mv0, mv1), fmaxf(mv2, mv3));
  const float w0 = __builtin_amdgcn_exp2f(mv0 - M);
  const float w1 = (nc > 1) ? __builtin_amdgcn_exp2f(mv1 - M) : 0.f;
  const float w2 = (nc > 2) ? __builtin_amdgcn_exp2f(mv2 - M) : 0.f;
  const float w3 = (nc > 3) ? __builtin_amdgcn_exp2f(mv3 - M) : 0.f;
  const float invL = 1.0f / (lv0 * w0 + lv1 * w1 + lv2 * w2 + lv3 * w3);

  float acc[16];
#pragma unroll
  for (int j = 0; j < 16; ++j) acc[j] = 0.f;

#pragma unroll
  for (int c = 0; c < 4; ++c) {
    if (c < nc) {
      const float fc = ((c == 0) ? w0 : (c == 1) ? w1 : (c == 2) ? w2 : w3) * invL;
      const bf16* src = po + ((long)(p0 + c) * 2048) + r * 64 + dc;
      const bf16x8 a0 = *reinterpret_cast<const bf16x8*>(src);
      const bf16x8 a1 = *reinterpret_cast<const bf16x8*>(src + 8);
#pragma unroll
      for (int j = 0; j < 8; ++j) {
        acc[j]     += (float)a0[j] * fc;
        acc[8 + j] += (float)a1[j] * fc;
      }
    }
  }

  const long q_abs = (long)qi * 32 + r;
  bf16* od = ao + q_abs * DMODEL + h * HDIM + dc;
  union { bf16 b[16]; u32x4 u[2]; } o;
#pragma unroll
  for (int j = 0; j < 16; ++j) o.b[j] = (bf16)acc[j];
  *reinterpret_cast<u32x4*>(od) = o.u[0];
  *reinterpret_cast<u32x4*>(od + 8) = o.u[1];
}

// ---------- launch ----------
extern "C" void kernel_launch(void* const* d_in, const int* in_sizes, int n_in,
                              void* d_out, int out_size, void* d_ws, size_t ws_size,
                              hipStream_t stream) {
  const float* x       = (const float*)d_in[0];
  const float* w_qkv   = (const float*)d_in[1];
  const float* w_out   = (const float*)d_in[2];
  const float* q_gamma = (const float*)d_in[3];
  const float* k_gamma = (const float*)d_in[4];
  // d_in[5] = mask (causal tril) — implemented analytically.

  char* ws = (char*)d_ws;
  // Region lifetimes (MB offsets):
  bf16* xb    = (bf16*)(ws);                     //  0..8   x bf16 (dead after gemm1)
  bf16* wqb   = (bf16*)(ws + (8ul  << 20));      //  8..20  w_qkv bf16 (dead after gemm1)
  bf16* wob   = (bf16*)(ws + (20ul << 20));      // 20..28  w_out bf16 (until gemm2)
  bf16* qkvpA = (bf16*)(ws + (28ul << 20));      // 28..40  qkv split-K partial 0
  bf16* qkvpB = (bf16*)(ws + (40ul << 20));      // 40..52  qkv split-K partial 1 (dead after rope/repack)
  bf16* qb    = (bf16*)(ws);                     //  0..8   Q (over dead xb)
  bf16* kfr   = (bf16*)(ws + (8ul  << 20));      //  8..10  K frag order (over dead wqb)
  bf16* vfr   = (bf16*)(ws + (10ul << 20));      // 10..12  V frag order
  bf16* po    = (bf16*)(ws + (28ul << 20));      // 28..48  attn partials (over dead qkvp)
  float* pm   = (float*)(ws + (48ul << 20));     // 48..48.7
  float* pl   = (float*)(ws + (49ul << 20));     // 49..49.7
  bf16* ao    = (bf16*)(ws + (52ul << 20));      // 52..60  attention out
  float* out  = (float*)d_out;

  cvt3_f32_bf16<<<2048, 256, 0, stream>>>(x, w_qkv, w_out, xb, wqb, wob);

  // QKV GEMM split-K=2: 768x2 blocks
  gemm_bt<bf16><<<dim3(QKV_N / 64, L_SEQ / 128, 2), 128, 0, stream>>>(xb, wqb, qkvpA, L_SEQ, QKV_N, DMODEL);

  rope_rms<<<(L_SEQ * 40) / 4, 256, 0, stream>>>(qkvpA, qkvpB, q_gamma, k_gamma, qb, kfr);
  repack_v<<<NKVH * (L_SEQ / 32), 256, 0, stream>>>(qkvpA, qkvpB, vfr);

  flash_attn<<<1280, 256, 0, stream>>>(qb, kfr, vfr, po, pm, pl);
  combine_split<<<1024, 256, 0, stream>>>(po, pm, pl, ao);

  gemm_bt<float><<<dim3(DMODEL / 64, L_SEQ / 128, 1), 128, 0, stream>>>(ao, wob, out, L_SEQ, DMODEL, DMODEL);
}

// Round 11
// 171.986 us; speedup vs baseline: 1.0045x; 1.0045x over previous
//
#include <hip/hip_runtime.h>

using bf16   = __bf16;
using bf16x4 = __bf16 __attribute__((ext_vector_type(4)));
using bf16x8 = __bf16 __attribute__((ext_vector_type(8)));
using f32x4  = float __attribute__((ext_vector_type(4)));
using f32x16 = float __attribute__((ext_vector_type(16)));
using u32x2  = unsigned int __attribute__((ext_vector_type(2)));
using u32x4  = unsigned int __attribute__((ext_vector_type(4)));

#define L_SEQ  2048
#define DMODEL 2048
#define NQH    32
#define NKVH   8
#define HDIM   64
#define QKV_N  3072   // NQH*HDIM + 2*NKVH*HDIM

// fragment-ordered K/V: per kv-head, 64 key-blocks of 32; each block = 4 frags
// of (64 lanes x 8 elems) = 2048 elems; per-head stride:
#define KVF_HSTRIDE (64 * 4 * 64 * 8)   // 131072 elems = 256 KiB

// ---------- helpers ----------
__device__ __forceinline__ void gload_lds16(const void* g, void* lds) {
  __builtin_amdgcn_global_load_lds((__attribute__((address_space(1))) void*)(g),
                                   (__attribute__((address_space(3))) void*)(lds),
                                   16, 0, 0);
}

__device__ __forceinline__ unsigned pack2(float a, float b) {
  union { bf16 h[2]; unsigned u; } x;
  x.h[0] = (bf16)a; x.h[1] = (bf16)b;
  return x.u;
}

// assemble the PV B-fragment from 8 per-lane P values (swapped layout)
__device__ __forceinline__ bf16x8 make_pfrag(float p0, float p1, float p2, float p3,
                                             float p4, float p5, float p6, float p7,
                                             int hi) {
  const unsigned W0 = pack2(p0, p1);
  const unsigned W1 = pack2(p2, p3);
  const unsigned W2 = pack2(p4, p5);
  const unsigned W3 = pack2(p6, p7);
  u32x4 pw;
#if __has_builtin(__builtin_amdgcn_permlane32_swap)
  {
    using i32x2 = int __attribute__((ext_vector_type(2)));
    const i32x2 r02 = __builtin_amdgcn_permlane32_swap((int)W0, (int)W2, false, false);
    const i32x2 r13 = __builtin_amdgcn_permlane32_swap((int)W1, (int)W3, false, false);
    pw = u32x4{ (unsigned)r02[0], (unsigned)r13[0], (unsigned)r02[1], (unsigned)r13[1] };
  }
#else
  {
    const unsigned X0 = (unsigned)__shfl_xor((int)W0, 32);
    const unsigned X1 = (unsigned)__shfl_xor((int)W1, 32);
    const unsigned X2 = (unsigned)__shfl_xor((int)W2, 32);
    const unsigned X3 = (unsigned)__shfl_xor((int)W3, 32);
    pw = u32x4{ hi ? X2 : W0, hi ? X3 : W1, hi ? W2 : X0, hi ? W3 : X1 };
  }
#endif
  return __builtin_bit_cast(bf16x8, pw);
}

// cumulative chunk count before qi (chunks of 16 subtiles)
__device__ __forceinline__ int chunk_base(int qi) {
  return (qi < 16) ? qi
       : (qi < 32) ? 16 + 2 * (qi - 16)
       : (qi < 48) ? 48 + 3 * (qi - 32)
                   : 96 + 4 * (qi - 48);
}

// ---------- fused fp32 -> bf16 convert (x, w_qkv, w_out in one launch) ----------
#define N4_X  (L_SEQ * DMODEL / 4)          // 1048576
#define N4_WQ (QKV_N * DMODEL / 4)          // 1572864
#define N4_WO (DMODEL * DMODEL / 4)         // 1048576
__global__ void cvt3_f32_bf16(const float* __restrict__ x, const float* __restrict__ wq,
                              const float* __restrict__ wo, bf16* __restrict__ xb,
                              bf16* __restrict__ wqb, bf16* __restrict__ wob) {
  const long stride = (long)gridDim.x * blockDim.x;
  const long ntot = N4_X + N4_WQ + N4_WO;
  for (long i = (long)blockIdx.x * blockDim.x + threadIdx.x; i < ntot; i += stride) {
    const float* src; bf16* dst; long j;
    if (i < N4_X)               { src = x;  dst = xb;  j = i; }
    else if (i < N4_X + N4_WQ)  { src = wq; dst = wqb; j = i - N4_X; }
    else                        { src = wo; dst = wob; j = i - N4_X - N4_WQ; }
    const float4 v = reinterpret_cast<const float4*>(src)[j];
    bf16x4 o = { (bf16)v.x, (bf16)v.y, (bf16)v.z, (bf16)v.w };
    reinterpret_cast<bf16x4*>(dst)[j] = o;
  }
}

// ---------- bf16 GEMM: C(MxN) = A(MxK) * B(NxK)^T, 128x64 tile, BK=64 ----------
// 2 waves per block; each wave computes the FULL 64x64 half-tile.
// Split-K via gridDim.z: block z covers K-range [z*K/gz, (z+1)*K/gz), writing
// its partial to C + z*M*N. gz=1 -> plain GEMM.
template <typename OutT>
__global__ __launch_bounds__(128)
void gemm_bt(const bf16* __restrict__ A, const bf16* __restrict__ B,
             OutT* __restrict__ C, int M, int N, int K) {
  __shared__ bf16 As[128 * 64];
  __shared__ bf16 Bs[64 * 64];
  const int tid = threadIdx.x;
  const int w = tid >> 6, l = tid & 63;
  const int lq = l & 15, lg = l >> 4;
  const long m0 = (long)blockIdx.y * 128;
  const long n0 = (long)blockIdx.x * 64;
  const int ks = K / gridDim.z;
  const int kb = blockIdx.z * ks;
  C += (long)blockIdx.z * M * N;

  const int lrow = l >> 3;                   // row within 8-row group (0..7)
  const int scol = ((l & 7) ^ lrow) << 3;    // pre-swizzled global element column

  f32x4 acc[4][4];
#pragma unroll
  for (int i = 0; i < 4; ++i)
#pragma unroll
    for (int j = 0; j < 4; ++j) acc[i][j] = f32x4{0.f, 0.f, 0.f, 0.f};

  for (int k0 = kb; k0 < kb + ks; k0 += 64) {
#pragma unroll
    for (int i = 0; i < 8; ++i) {
      const int r0 = (i * 2 + w) * 8;
      gload_lds16(A + (m0 + r0 + lrow) * (long)K + k0 + scol, &As[r0 * 64]);
    }
#pragma unroll
    for (int i = 0; i < 4; ++i) {
      const int r0 = (i * 2 + w) * 8;
      gload_lds16(B + (n0 + r0 + lrow) * (long)K + k0 + scol, &Bs[r0 * 64]);
    }
    __syncthreads();
#pragma unroll
    for (int kk = 0; kk < 2; ++kk) {
      bf16x8 af[4], bfr[4];
#pragma unroll
      for (int t = 0; t < 4; ++t) {
        const int rowA = w * 64 + t * 16 + lq;
        const int blkA = (kk * 4 + lg) ^ (rowA & 7);
        af[t] = *reinterpret_cast<const bf16x8*>(&As[rowA * 64 + blkA * 8]);
        const int rowB = t * 16 + lq;
        const int blkB = (kk * 4 + lg) ^ (rowB & 7);
        bfr[t] = *reinterpret_cast<const bf16x8*>(&Bs[rowB * 64 + blkB * 8]);
      }
#pragma unroll
      for (int mt = 0; mt < 4; ++mt)
#pragma unroll
        for (int nt = 0; nt < 4; ++nt)
          acc[mt][nt] = __builtin_amdgcn_mfma_f32_16x16x32_bf16(af[mt], bfr[nt], acc[mt][nt], 0, 0, 0);
    }
    __syncthreads();
  }

#pragma unroll
  for (int mt = 0; mt < 4; ++mt)
#pragma unroll
    for (int r = 0; r < 4; ++r) {
      const long row = m0 + w * 64 + mt * 16 + lg * 4 + r;
#pragma unroll
      for (int nt = 0; nt < 4; ++nt) {
        const long col = n0 + nt * 16 + lq;
        C[row * (long)N + col] = (OutT)acc[mt][nt][r];
      }
    }
}

// ---------- RoPE + RMSNorm for Q and K (reads 2 split-K partials, adds) ----------
// Q scaled by SCALE*log2(e); K written directly in MFMA-fragment order.
__global__ __launch_bounds__(256)
void rope_rms(const bf16* __restrict__ pA, const bf16* __restrict__ pB,
              const float* __restrict__ qg, const float* __restrict__ kg,
              bf16* __restrict__ qo, bf16* __restrict__ kfr) {
  const int gid = blockIdx.x * 4 + (threadIdx.x >> 6);
  const int lane = threadIdx.x & 63;
  const int pos = gid / 40;
  const int hh = gid % 40;            // 0..31 q heads, 32..39 k heads
  const bool isq = hh < 32;
  const int col = isq ? hh * HDIM : NQH * HDIM + (hh - 32) * HDIM;

  const long idx = (long)pos * QKV_N + col + lane;
  float x = (float)pA[idx] + (float)pB[idx];
  float p = __shfl_xor(x, 1);
  const float fi = (float)(lane & ~1) * (1.0f / 64.0f);
  const float inv = powf(50000.0f, -fi);
  const float ang = (float)pos * inv;
  const float sn = sinf(ang), cs = cosf(ang);
  const float r = (lane & 1) ? (p * sn + x * cs) : (x * cs - p * sn);

  float ss = r * r;
#pragma unroll
  for (int off = 1; off < 64; off <<= 1) ss += __shfl_xor(ss, off);
  const float scl = rsqrtf(ss * (1.0f / 64.0f) + 1e-5f);
  const float g = isq ? qg[lane] : kg[lane];
  const float o = r * scl * g;

  if (isq) {
    qo[(long)pos * DMODEL + hh * HDIM + lane] = (bf16)(o * 0.18033688011112042f);
  } else {
    const int kvh = hh - 32;
    const int d = lane;
    const int lp = (pos & 31) + (((d >> 3) & 1) << 5);
    const long kidx = ((((long)kvh * 64 + (pos >> 5)) * 4 + (d >> 4)) * 64 + lp) * 8 + (d & 7);
    kfr[kidx] = (bf16)o;
  }
}

// ---------- V repack (reads 2 split-K partials): -> vfr MFMA-fragment order ----------
__global__ __launch_bounds__(256)
void repack_v(const bf16* __restrict__ pA, const bf16* __restrict__ pB,
              bf16* __restrict__ vfr) {
  __shared__ bf16 t[32][72];
  const int kvh = blockIdx.x >> 6;
  const int kb = blockIdx.x & 63;
  const int tid = threadIdx.x;

  {
    const int row = tid >> 3;
    const int cc = (tid & 7) * 8;
    const long goff = (long)(kb * 32 + row) * QKV_N + (NQH * HDIM + NKVH * HDIM) + kvh * HDIM + cc;
    const bf16x8 a = *reinterpret_cast<const bf16x8*>(pA + goff);
    const bf16x8 b = *reinterpret_cast<const bf16x8*>(pB + goff);
    bf16x8 s;
#pragma unroll
    for (int e = 0; e < 8; ++e) s[e] = (bf16)((float)a[e] + (float)b[e]);
    *reinterpret_cast<bf16x8*>(&t[row][cc]) = s;
  }
  __syncthreads();

  const int f = tid >> 6, l = tid & 63;
  const int s = f >> 1, dh = f & 1;
  const int hi = l >> 5, l31 = l & 31;
  union { bf16 b[8]; u32x4 u; } o;
#pragma unroll
  for (int e = 0; e < 8; ++e) o.b[e] = t[s * 16 + hi * 8 + e][dh * 32 + l31];
  bf16* od = vfr + (((long)(kvh * 64 + kb) * 4 + f) * 64 + l) * 8;
  *reinterpret_cast<u32x4*>(od) = o.u;
}

// ---------- flash attention (causal, GQA), fine split-K, XCD-pinned ----------
// 1280 blocks; kvh = blockIdx%8 pins K/V to one XCD's L2; biggest chunks
// dispatched FIRST (g reversed) so small chunks backfill the tail.
// K/V staged to LDS once per block in PAIRS of 32-key subtiles (KVBLK=64):
// one barrier per 64 keys, softmax bookkeeping amortized, two independent
// QK^T MFMA chains in flight (ILP-2).
__global__ __launch_bounds__(256)
void flash_attn(const bf16* __restrict__ Q, const bf16* __restrict__ Kfr,
                const bf16* __restrict__ Vfr,
                bf16* __restrict__ po, float* __restrict__ pm, float* __restrict__ pl) {
  __shared__ bf16 Ks[2][4096];
  __shared__ bf16 Vs[2][4096];
  const int tid = threadIdx.x;
  const int w = tid >> 6, l = tid & 63;
  const int lane31 = l & 31, hi = l >> 5;
  const int bb = blockIdx.x;
  const int kvh = bb & 7;               // XCD pin
  const int g = 159 - (bb >> 3);        // 0..159, biggest chunks first

  // invert cumulative chunk id -> (qi, c)
  int qi, c;
  if (g < 16)      { qi = g;                  c = 0; }
  else if (g < 48) { qi = 16 + ((g - 16) >> 1); c = (g - 16) & 1; }
  else if (g < 96) { qi = 32 + (g - 48) / 3;    c = (g - 48) % 3; }
  else             { qi = 48 + ((g - 96) >> 2); c = (g - 96) & 3; }

  const int h = kvh * 4 + w;            // wave -> q-head
  const int s0 = c * 16;
  const int s1 = min(qi + 1, s0 + 16);
  const int pidx = h * 160 + g;         // g == chunk_base(qi) + c

  const int q0 = qi * 32;
  const int q_abs = q0 + lane31;
  const int l8 = l * 8;

  const bf16* kfrh = Kfr + (long)kvh * KVF_HSTRIDE;
  const bf16* vfrh = Vfr + (long)kvh * KVF_HSTRIDE;

  // Q fragments (B-frag of ST): lane -> Q[q0+lane31][cc*16 + hi*8 + e]
  const bf16* qrow = Q + (long)q_abs * DMODEL + h * HDIM + hi * 8;
  bf16x8 qf[4];
#pragma unroll
  for (int cc = 0; cc < 4; ++cc) qf[cc] = *reinterpret_cast<const bf16x8*>(qrow + cc * 16);

  f32x16 o0, o1;
#pragma unroll
  for (int r = 0; r < 16; ++r) { o0[r] = 0.f; o1[r] = 0.f; }
  float m = -3.0e38f, lsum = 0.f;

  // prologue: stage pair (s0, s0+1) into buf 0 (16 KB, 4 x 16B per thread)
  {
    const long base = (long)s0 * 2048;
    gload_lds16(kfrh + base + tid * 8,        &Ks[0][tid * 8]);
    gload_lds16(kfrh + base + 2048 + tid * 8, &Ks[0][2048 + tid * 8]);
    gload_lds16(vfrh + base + tid * 8,        &Vs[0][tid * 8]);
    gload_lds16(vfrh + base + 2048 + tid * 8, &Vs[0][2048 + tid * 8]);
  }
  __syncthreads();

  int buf = 0;
  int sti = s0;
  for (; sti + 1 < s1; sti += 2) {
    // stage NEXT pair into the other buffer (in flight across compute)
    if (sti + 2 < s1) {
      const long base = (long)(sti + 2) * 2048;
      gload_lds16(kfrh + base + tid * 8,        &Ks[buf ^ 1][tid * 8]);
      gload_lds16(kfrh + base + 2048 + tid * 8, &Ks[buf ^ 1][2048 + tid * 8]);
      gload_lds16(vfrh + base + tid * 8,        &Vs[buf ^ 1][tid * 8]);
      gload_lds16(vfrh + base + 2048 + tid * 8, &Vs[buf ^ 1][2048 + tid * 8]);
    }

    // ---- two independent ST chains over 4 d-chunks each ----
    f32x16 sa, sb;
#pragma unroll
    for (int r = 0; r < 16; ++r) { sa[r] = 0.f; sb[r] = 0.f; }
#pragma unroll
    for (int cc = 0; cc < 4; ++cc) {
      const bf16x8 ka = *reinterpret_cast<const bf16x8*>(&Ks[buf][cc * 512 + l8]);
      const bf16x8 kb = *reinterpret_cast<const bf16x8*>(&Ks[buf][2048 + cc * 512 + l8]);
      sa = __builtin_amdgcn_mfma_f32_32x32x16_bf16(ka, qf[cc], sa, 0, 0, 0);
      sb = __builtin_amdgcn_mfma_f32_32x32x16_bf16(kb, qf[cc], sb, 0, 0, 0);
    }

    // V frags for subtile a (LDS reads issue early)
    const bf16x8 va0 = *reinterpret_cast<const bf16x8*>(&Vs[buf][l8]);
    const bf16x8 vb0 = *reinterpret_cast<const bf16x8*>(&Vs[buf][512 + l8]);
    const bf16x8 va1 = *reinterpret_cast<const bf16x8*>(&Vs[buf][1024 + l8]);
    const bf16x8 vb1 = *reinterpret_cast<const bf16x8*>(&Vs[buf][1536 + l8]);

    // ---- causal mask (diagonal pair only) ----
    const int kb0a = sti * 32, kb0b = kb0a + 32;
    if (kb0b + 31 > q0) {
#pragma unroll
      for (int r = 0; r < 16; ++r) {
        const int krel = (r & 3) + 8 * (r >> 2) + 4 * hi;
        if (kb0a + krel > q_abs) sa[r] = -3.0e38f;
        if (kb0b + krel > q_abs) sb[r] = -3.0e38f;
      }
    }

    // ---- shared online softmax over 64 keys ----
    float t[16];
#pragma unroll
    for (int r = 0; r < 16; ++r) t[r] = fmaxf(sa[r], sb[r]);
#pragma unroll
    for (int s = 8; s > 0; s >>= 1)
#pragma unroll
      for (int r = 0; r < 8; ++r) if (r < s) t[r] = fmaxf(t[r], t[r + s]);
    const float mx = fmaxf(t[0], __shfl_xor(t[0], 32));

    if (!__all(mx - m <= 8.0f)) {        // defer-max, THR=8
      const float mn = fmaxf(m, mx);
      const float al = __builtin_amdgcn_exp2f(m - mn);
      m = mn; lsum *= al;
#pragma unroll
      for (int r = 0; r < 16; ++r) { o0[r] *= al; o1[r] *= al; }
    }
    float rs = 0.f;
#pragma unroll
    for (int r = 0; r < 16; ++r) { sa[r] = __builtin_amdgcn_exp2f(sa[r] - m); rs += sa[r]; }
#pragma unroll
    for (int r = 0; r < 16; ++r) { sb[r] = __builtin_amdgcn_exp2f(sb[r] - m); rs += sb[r]; }
    rs += __shfl_xor(rs, 32);
    lsum += rs;

    // ---- PV subtile a ----
    {
      const bf16x8 pf0 = make_pfrag(sa[0], sa[1], sa[2], sa[3], sa[4], sa[5], sa[6], sa[7], hi);
      o0 = __builtin_amdgcn_mfma_f32_32x32x16_bf16(va0, pf0, o0, 0, 0, 0);
      o1 = __builtin_amdgcn_mfma_f32_32x32x16_bf16(vb0, pf0, o1, 0, 0, 0);
      const bf16x8 pf1 = make_pfrag(sa[8], sa[9], sa[10], sa[11], sa[12], sa[13], sa[14], sa[15], hi);
      o0 = __builtin_amdgcn_mfma_f32_32x32x16_bf16(va1, pf1, o0, 0, 0, 0);
      o1 = __builtin_amdgcn_mfma_f32_32x32x16_bf16(vb1, pf1, o1, 0, 0, 0);
    }
    // ---- PV subtile b (V frags loaded here to cap register peak) ----
    {
      const bf16x8 wa0 = *reinterpret_cast<const bf16x8*>(&Vs[buf][2048 + l8]);
      const bf16x8 wb0 = *reinterpret_cast<const bf16x8*>(&Vs[buf][2560 + l8]);
      const bf16x8 wa1 = *reinterpret_cast<const bf16x8*>(&Vs[buf][3072 + l8]);
      const bf16x8 wb1 = *reinterpret_cast<const bf16x8*>(&Vs[buf][3584 + l8]);
      const bf16x8 pf0 = make_pfrag(sb[0], sb[1], sb[2], sb[3], sb[4], sb[5], sb[6], sb[7], hi);
      o0 = __builtin_amdgcn_mfma_f32_32x32x16_bf16(wa0, pf0, o0, 0, 0, 0);
      o1 = __builtin_amdgcn_mfma_f32_32x32x16_bf16(wb0, pf0, o1, 0, 0, 0);
      const bf16x8 pf1 = make_pfrag(sb[8], sb[9], sb[10], sb[11], sb[12], sb[13], sb[14], sb[15], hi);
      o0 = __builtin_amdgcn_mfma_f32_32x32x16_bf16(wa1, pf1, o0, 0, 0, 0);
      o1 = __builtin_amdgcn_mfma_f32_32x32x16_bf16(wb1, pf1, o1, 0, 0, 0);
    }

    __syncthreads();                     // drains next stage, frees buf
    buf ^= 1;
  }

  // ---- tail: single 32-key subtile (slot 0 of current buf) ----
  if (sti < s1) {
    const int kb0 = sti * 32;
    f32x16 st;
#pragma unroll
    for (int r = 0; r < 16; ++r) st[r] = 0.f;
#pragma unroll
    for (int cc = 0; cc < 4; ++cc) {
      const bf16x8 ka = *reinterpret_cast<const bf16x8*>(&Ks[buf][cc * 512 + l8]);
      st = __builtin_amdgcn_mfma_f32_32x32x16_bf16(ka, qf[cc], st, 0, 0, 0);
    }
    const bf16x8 va0 = *reinterpret_cast<const bf16x8*>(&Vs[buf][l8]);
    const bf16x8 vb0 = *reinterpret_cast<const bf16x8*>(&Vs[buf][512 + l8]);
    const bf16x8 va1 = *reinterpret_cast<const bf16x8*>(&Vs[buf][1024 + l8]);
    const bf16x8 vb1 = *reinterpret_cast<const bf16x8*>(&Vs[buf][1536 + l8]);

    if (kb0 + 31 > q0) {
#pragma unroll
      for (int r = 0; r < 16; ++r) {
        const int k_abs = kb0 + (r & 3) + 8 * (r >> 2) + 4 * hi;
        if (k_abs > q_abs) st[r] = -3.0e38f;
      }
    }

    float t[8];
#pragma unroll
    for (int r = 0; r < 8; ++r) t[r] = fmaxf(st[r], st[r + 8]);
#pragma unroll
    for (int s = 4; s > 0; s >>= 1)
#pragma unroll
      for (int r = 0; r < 4; ++r) if (r < s) t[r] = fmaxf(t[r], t[r + s]);
    const float mx = fmaxf(t[0], __shfl_xor(t[0], 32));

    if (!__all(mx - m <= 8.0f)) {
      const float mn = fmaxf(m, mx);
      const float al = __builtin_amdgcn_exp2f(m - mn);
      m = mn; lsum *= al;
#pragma unroll
      for (int r = 0; r < 16; ++r) { o0[r] *= al; o1[r] *= al; }
    }
    float rs = 0.f;
#pragma unroll
    for (int r = 0; r < 16; ++r) { st[r] = __builtin_amdgcn_exp2f(st[r] - m); rs += st[r]; }
    rs += __shfl_xor(rs, 32);
    lsum += rs;

    const bf16x8 pf0 = make_pfrag(st[0], st[1], st[2], st[3], st[4], st[5], st[6], st[7], hi);
    o0 = __builtin_amdgcn_mfma_f32_32x32x16_bf16(va0, pf0, o0, 0, 0, 0);
    o1 = __builtin_amdgcn_mfma_f32_32x32x16_bf16(vb0, pf0, o1, 0, 0, 0);
    const bf16x8 pf1 = make_pfrag(st[8], st[9], st[10], st[11], st[12], st[13], st[14], st[15], hi);
    o0 = __builtin_amdgcn_mfma_f32_32x32x16_bf16(va1, pf1, o0, 0, 0, 0);
    o1 = __builtin_amdgcn_mfma_f32_32x32x16_bf16(vb1, pf1, o1, 0, 0, 0);
  }

  // ---- store bf16 partial (unnormalized) + f32 stats ----
  bf16* pbase = po + (long)pidx * 2048 + lane31 * 64;
#pragma unroll
  for (int gg = 0; gg < 4; ++gg) {
    const int d0 = 8 * gg + 4 * hi;
    u32x2 s0v = { pack2(o0[4 * gg + 0], o0[4 * gg + 1]),
                  pack2(o0[4 * gg + 2], o0[4 * gg + 3]) };
    u32x2 s1v = { pack2(o1[4 * gg + 0], o1[4 * gg + 1]),
                  pack2(o1[4 * gg + 2], o1[4 * gg + 3]) };
    *reinterpret_cast<u32x2*>(pbase + d0) = s0v;
    *reinterpret_cast<u32x2*>(pbase + 32 + d0) = s1v;
  }
  if (hi == 0) {
    pm[pidx * 32 + lane31] = m;
    pl[pidx * 32 + lane31] = lsum;
  }
}

// ---------- combine partials: ao[q] = Σ_c O_c·2^(m_c−M) / Σ_c l_c·2^(m_c−M) ----------
__global__ __launch_bounds__(256)
void combine_split(const bf16* __restrict__ po, const float* __restrict__ pm,
                   const float* __restrict__ pl, bf16* __restrict__ ao) {
  const int t = blockIdx.x * 2 + (threadIdx.x >> 7);
  const int tid7 = threadIdx.x & 127;
  const int r = tid7 >> 2;                 // q row 0..31
  const int dc = (tid7 & 3) * 16;          // d chunk
  const int h = t >> 6, qi = t & 63;
  const int nc = 1 + (qi >> 4);
  const int p0 = h * 160 + chunk_base(qi);

  float mv0 = -3e38f, mv1 = -3e38f, mv2 = -3e38f, mv3 = -3e38f;
  float lv0 = 0.f, lv1 = 0.f, lv2 = 0.f, lv3 = 0.f;
  mv0 = pm[(p0 + 0) * 32 + r];              lv0 = pl[(p0 + 0) * 32 + r];
  if (nc > 1) { mv1 = pm[(p0 + 1) * 32 + r]; lv1 = pl[(p0 + 1) * 32 + r]; }
  if (nc > 2) { mv2 = pm[(p0 + 2) * 32 + r]; lv2 = pl[(p0 + 2) * 32 + r]; }
  if (nc > 3) { mv3 = pm[(p0 + 3) * 32 + r]; lv3 = pl[(p0 + 3) * 32 + r]; }
  const float M = fmaxf(fmaxf(mv0, mv1), fmaxf(mv2, mv3));
  const float w0 = __builtin_amdgcn_exp2f(mv0 - M);
  const float w1 = (nc > 1) ? __builtin_amdgcn_exp2f(mv1 - M) : 0.f;
  const float w2 = (nc > 2) ? __builtin_amdgcn_exp2f(mv2 - M) : 0.f;
  const float w3 = (nc > 3) ? __builtin_amdgcn_exp2f(mv3 - M) : 0.f;
  const float invL = 1.0f / (lv0 * w0 + lv1 * w1 + lv2 * w2 + lv3 * w3);

  float acc[16];
#pragma unroll
  for (int j = 0; j < 16; ++j) acc[j] = 0.f;

#pragma unroll
  for (int c = 0; c < 4; ++c) {
    if (c < nc) {
      const float fc = ((c == 0) ? w0 : (c == 1) ? w1 : (c == 2) ? w2 : w3) * invL;
      const bf16* src = po + ((long)(p0 + c) * 2048) + r * 64 + dc;
      const bf16x8 a0 = *reinterpret_cast<const bf16x8*>(src);
      const bf16x8 a1 = *reinterpret_cast<const bf16x8*>(src + 8);
#pragma unroll
      for (int j = 0; j < 8; ++j) {
        acc[j]     += (float)a0[j] * fc;
        acc[8 + j] += (float)a1[j] * fc;
      }
    }
  }

  const long q_abs = (long)qi * 32 + r;
  bf16* od = ao + q_abs * DMODEL + h * HDIM + dc;
  union { bf16 b[16]; u32x4 u[2]; } o;
#pragma unroll
  for (int j = 0; j < 16; ++j) o.b[j] = (bf16)acc[j];
  *reinterpret_cast<u32x4*>(od) = o.u[0];
  *reinterpret_cast<u32x4*>(od + 8) = o.u[1];
}

// ---------- launch ----------
extern "C" void kernel_launch(void* const* d_in, const int* in_sizes, int n_in,
                              void* d_out, int out_size, void* d_ws, size_t ws_size,
                              hipStream_t stream) {
  const float* x       = (const float*)d_in[0];
  const float* w_qkv   = (const float*)d_in[1];
  const float* w_out   = (const float*)d_in[2];
  const float* q_gamma = (const float*)d_in[3];
  const float* k_gamma = (const float*)d_in[4];
  // d_in[5] = mask (causal tril) — implemented analytically.

  char* ws = (char*)d_ws;
  // Region lifetimes (MB offsets):
  bf16* xb    = (bf16*)(ws);                     //  0..8   x bf16 (dead after gemm1)
  bf16* wqb   = (bf16*)(ws + (8ul  << 20));      //  8..20  w_qkv bf16 (dead after gemm1)
  bf16* wob   = (bf16*)(ws + (20ul << 20));      // 20..28  w_out bf16 (until gemm2)
  bf16* qkvpA = (bf16*)(ws + (28ul << 20));      // 28..40  qkv split-K partial 0
  bf16* qkvpB = (bf16*)(ws + (40ul << 20));      // 40..52  qkv split-K partial 1 (dead after rope/repack)
  bf16* qb    = (bf16*)(ws);                     //  0..8   Q (over dead xb)
  bf16* kfr   = (bf16*)(ws + (8ul  << 20));      //  8..10  K frag order (over dead wqb)
  bf16* vfr   = (bf16*)(ws + (10ul << 20));      // 10..12  V frag order
  bf16* po    = (bf16*)(ws + (28ul << 20));      // 28..48  attn partials (over dead qkvp)
  float* pm   = (float*)(ws + (48ul << 20));     // 48..48.7
  float* pl   = (float*)(ws + (49ul << 20));     // 49..49.7
  bf16* ao    = (bf16*)(ws + (52ul << 20));      // 52..60  attention out
  float* out  = (float*)d_out;

  cvt3_f32_bf16<<<2048, 256, 0, stream>>>(x, w_qkv, w_out, xb, wqb, wob);

  // QKV GEMM split-K=2: 768x2 blocks
  gemm_bt<bf16><<<dim3(QKV_N / 64, L_SEQ / 128, 2), 128, 0, stream>>>(xb, wqb, qkvpA, L_SEQ, QKV_N, DMODEL);

  rope_rms<<<(L_SEQ * 40) / 4, 256, 0, stream>>>(qkvpA, qkvpB, q_gamma, k_gamma, qb, kfr);
  repack_v<<<NKVH * (L_SEQ / 32), 256, 0, stream>>>(qkvpA, qkvpB, vfr);

  flash_attn<<<1280, 256, 0, stream>>>(qb, kfr, vfr, po, pm, pl);
  combine_split<<<1024, 256, 0, stream>>>(po, pm, pl, ao);

  gemm_bt<float><<<dim3(DMODEL / 64, L_SEQ / 128, 1), 128, 0, stream>>>(ao, wob, out, L_SEQ, DMODEL, DMODEL);
}

// Round 12
// 168.676 us; speedup vs baseline: 1.0243x; 1.0196x over previous
//
#include <hip/hip_runtime.h>

using bf16   = __bf16;
using bf16x4 = __bf16 __attribute__((ext_vector_type(4)));
using bf16x8 = __bf16 __attribute__((ext_vector_type(8)));
using f32x4  = float __attribute__((ext_vector_type(4)));
using f32x16 = float __attribute__((ext_vector_type(16)));
using u32x2  = unsigned int __attribute__((ext_vector_type(2)));
using u32x4  = unsigned int __attribute__((ext_vector_type(4)));

#define L_SEQ  2048
#define DMODEL 2048
#define NQH    32
#define NKVH   8
#define HDIM   64
#define QKV_N  3072   // NQH*HDIM + 2*NKVH*HDIM

// fragment-ordered K/V: per kv-head, 64 key-blocks of 32; each block = 4 frags
// of (64 lanes x 8 elems) = 2048 elems; per-head stride:
#define KVF_HSTRIDE (64 * 4 * 64 * 8)   // 131072 elems = 256 KiB

// ---------- helpers ----------
__device__ __forceinline__ void gload_lds16(const void* g, void* lds) {
  __builtin_amdgcn_global_load_lds((__attribute__((address_space(1))) void*)(g),
                                   (__attribute__((address_space(3))) void*)(lds),
                                   16, 0, 0);
}

__device__ __forceinline__ unsigned pack2(float a, float b) {
  union { bf16 h[2]; unsigned u; } x;
  x.h[0] = (bf16)a; x.h[1] = (bf16)b;
  return x.u;
}

// assemble the PV B-fragment from 8 per-lane P values (swapped layout)
__device__ __forceinline__ bf16x8 make_pfrag(float p0, float p1, float p2, float p3,
                                             float p4, float p5, float p6, float p7,
                                             int hi) {
  const unsigned W0 = pack2(p0, p1);
  const unsigned W1 = pack2(p2, p3);
  const unsigned W2 = pack2(p4, p5);
  const unsigned W3 = pack2(p6, p7);
  u32x4 pw;
#if __has_builtin(__builtin_amdgcn_permlane32_swap)
  {
    using i32x2 = int __attribute__((ext_vector_type(2)));
    const i32x2 r02 = __builtin_amdgcn_permlane32_swap((int)W0, (int)W2, false, false);
    const i32x2 r13 = __builtin_amdgcn_permlane32_swap((int)W1, (int)W3, false, false);
    pw = u32x4{ (unsigned)r02[0], (unsigned)r13[0], (unsigned)r02[1], (unsigned)r13[1] };
  }
#else
  {
    const unsigned X0 = (unsigned)__shfl_xor((int)W0, 32);
    const unsigned X1 = (unsigned)__shfl_xor((int)W1, 32);
    const unsigned X2 = (unsigned)__shfl_xor((int)W2, 32);
    const unsigned X3 = (unsigned)__shfl_xor((int)W3, 32);
    pw = u32x4{ hi ? X2 : W0, hi ? X3 : W1, hi ? W2 : X0, hi ? W3 : X1 };
  }
#endif
  return __builtin_bit_cast(bf16x8, pw);
}

// cumulative chunk count before qi (chunks of 16 subtiles)
__device__ __forceinline__ int chunk_base(int qi) {
  return (qi < 16) ? qi
       : (qi < 32) ? 16 + 2 * (qi - 16)
       : (qi < 48) ? 48 + 3 * (qi - 32)
                   : 96 + 4 * (qi - 48);
}

// ---------- fused fp32 -> bf16 convert (x, w_qkv, w_out in one launch) ----------
#define N4_X  (L_SEQ * DMODEL / 4)          // 1048576
#define N4_WQ (QKV_N * DMODEL / 4)          // 1572864
#define N4_WO (DMODEL * DMODEL / 4)         // 1048576
__global__ void cvt3_f32_bf16(const float* __restrict__ x, const float* __restrict__ wq,
                              const float* __restrict__ wo, bf16* __restrict__ xb,
                              bf16* __restrict__ wqb, bf16* __restrict__ wob) {
  const long stride = (long)gridDim.x * blockDim.x;
  const long ntot = N4_X + N4_WQ + N4_WO;
  for (long i = (long)blockIdx.x * blockDim.x + threadIdx.x; i < ntot; i += stride) {
    const float* src; bf16* dst; long j;
    if (i < N4_X)               { src = x;  dst = xb;  j = i; }
    else if (i < N4_X + N4_WQ)  { src = wq; dst = wqb; j = i - N4_X; }
    else                        { src = wo; dst = wob; j = i - N4_X - N4_WQ; }
    const float4 v = reinterpret_cast<const float4*>(src)[j];
    bf16x4 o = { (bf16)v.x, (bf16)v.y, (bf16)v.z, (bf16)v.w };
    reinterpret_cast<bf16x4*>(dst)[j] = o;
  }
}

// ---------- bf16 GEMM: C(MxN) = A(MxK) * B(NxK)^T, 128x64 tile, BK=64 ----------
// 2 waves per block; each wave computes the FULL 64x64 half-tile.
// Split-K via gridDim.z: block z covers K-range [z*K/gz, (z+1)*K/gz), writing
// its partial to C + z*M*N. gz=1 -> plain GEMM.
template <typename OutT>
__global__ __launch_bounds__(128)
void gemm_bt(const bf16* __restrict__ A, const bf16* __restrict__ B,
             OutT* __restrict__ C, int M, int N, int K) {
  __shared__ bf16 As[128 * 64];
  __shared__ bf16 Bs[64 * 64];
  const int tid = threadIdx.x;
  const int w = tid >> 6, l = tid & 63;
  const int lq = l & 15, lg = l >> 4;
  const long m0 = (long)blockIdx.y * 128;
  const long n0 = (long)blockIdx.x * 64;
  const int ks = K / gridDim.z;
  const int kb = blockIdx.z * ks;
  C += (long)blockIdx.z * M * N;

  const int lrow = l >> 3;                   // row within 8-row group (0..7)
  const int scol = ((l & 7) ^ lrow) << 3;    // pre-swizzled global element column

  f32x4 acc[4][4];
#pragma unroll
  for (int i = 0; i < 4; ++i)
#pragma unroll
    for (int j = 0; j < 4; ++j) acc[i][j] = f32x4{0.f, 0.f, 0.f, 0.f};

  for (int k0 = kb; k0 < kb + ks; k0 += 64) {
#pragma unroll
    for (int i = 0; i < 8; ++i) {
      const int r0 = (i * 2 + w) * 8;
      gload_lds16(A + (m0 + r0 + lrow) * (long)K + k0 + scol, &As[r0 * 64]);
    }
#pragma unroll
    for (int i = 0; i < 4; ++i) {
      const int r0 = (i * 2 + w) * 8;
      gload_lds16(B + (n0 + r0 + lrow) * (long)K + k0 + scol, &Bs[r0 * 64]);
    }
    __syncthreads();
#pragma unroll
    for (int kk = 0; kk < 2; ++kk) {
      bf16x8 af[4], bfr[4];
#pragma unroll
      for (int t = 0; t < 4; ++t) {
        const int rowA = w * 64 + t * 16 + lq;
        const int blkA = (kk * 4 + lg) ^ (rowA & 7);
        af[t] = *reinterpret_cast<const bf16x8*>(&As[rowA * 64 + blkA * 8]);
        const int rowB = t * 16 + lq;
        const int blkB = (kk * 4 + lg) ^ (rowB & 7);
        bfr[t] = *reinterpret_cast<const bf16x8*>(&Bs[rowB * 64 + blkB * 8]);
      }
#pragma unroll
      for (int mt = 0; mt < 4; ++mt)
#pragma unroll
        for (int nt = 0; nt < 4; ++nt)
          acc[mt][nt] = __builtin_amdgcn_mfma_f32_16x16x32_bf16(af[mt], bfr[nt], acc[mt][nt], 0, 0, 0);
    }
    __syncthreads();
  }

#pragma unroll
  for (int mt = 0; mt < 4; ++mt)
#pragma unroll
    for (int r = 0; r < 4; ++r) {
      const long row = m0 + w * 64 + mt * 16 + lg * 4 + r;
#pragma unroll
      for (int nt = 0; nt < 4; ++nt) {
        const long col = n0 + nt * 16 + lq;
        C[row * (long)N + col] = (OutT)acc[mt][nt][r];
      }
    }
}

// ---------- RoPE + RMSNorm for Q and K (reads 2 split-K partials, adds) ----------
// Q scaled by SCALE*log2(e); K written directly in MFMA-fragment order.
__global__ __launch_bounds__(256)
void rope_rms(const bf16* __restrict__ pA, const bf16* __restrict__ pB,
              const float* __restrict__ qg, const float* __restrict__ kg,
              bf16* __restrict__ qo, bf16* __restrict__ kfr) {
  const int gid = blockIdx.x * 4 + (threadIdx.x >> 6);
  const int lane = threadIdx.x & 63;
  const int pos = gid / 40;
  const int hh = gid % 40;            // 0..31 q heads, 32..39 k heads
  const bool isq = hh < 32;
  const int col = isq ? hh * HDIM : NQH * HDIM + (hh - 32) * HDIM;

  const long idx = (long)pos * QKV_N + col + lane;
  float x = (float)pA[idx] + (float)pB[idx];
  float p = __shfl_xor(x, 1);
  const float fi = (float)(lane & ~1) * (1.0f / 64.0f);
  const float inv = powf(50000.0f, -fi);
  const float ang = (float)pos * inv;
  const float sn = sinf(ang), cs = cosf(ang);
  const float r = (lane & 1) ? (p * sn + x * cs) : (x * cs - p * sn);

  float ss = r * r;
#pragma unroll
  for (int off = 1; off < 64; off <<= 1) ss += __shfl_xor(ss, off);
  const float scl = rsqrtf(ss * (1.0f / 64.0f) + 1e-5f);
  const float g = isq ? qg[lane] : kg[lane];
  const float o = r * scl * g;

  if (isq) {
    qo[(long)pos * DMODEL + hh * HDIM + lane] = (bf16)(o * 0.18033688011112042f);
  } else {
    const int kvh = hh - 32;
    const int d = lane;
    const int lp = (pos & 31) + (((d >> 3) & 1) << 5);
    const long kidx = ((((long)kvh * 64 + (pos >> 5)) * 4 + (d >> 4)) * 64 + lp) * 8 + (d & 7);
    kfr[kidx] = (bf16)o;
  }
}

// ---------- V repack (reads 2 split-K partials): -> vfr MFMA-fragment order ----------
__global__ __launch_bounds__(256)
void repack_v(const bf16* __restrict__ pA, const bf16* __restrict__ pB,
              bf16* __restrict__ vfr) {
  __shared__ bf16 t[32][72];
  const int kvh = blockIdx.x >> 6;
  const int kb = blockIdx.x & 63;
  const int tid = threadIdx.x;

  {
    const int row = tid >> 3;
    const int cc = (tid & 7) * 8;
    const long goff = (long)(kb * 32 + row) * QKV_N + (NQH * HDIM + NKVH * HDIM) + kvh * HDIM + cc;
    const bf16x8 a = *reinterpret_cast<const bf16x8*>(pA + goff);
    const bf16x8 b = *reinterpret_cast<const bf16x8*>(pB + goff);
    bf16x8 s;
#pragma unroll
    for (int e = 0; e < 8; ++e) s[e] = (bf16)((float)a[e] + (float)b[e]);
    *reinterpret_cast<bf16x8*>(&t[row][cc]) = s;
  }
  __syncthreads();

  const int f = tid >> 6, l = tid & 63;
  const int s = f >> 1, dh = f & 1;
  const int hi = l >> 5, l31 = l & 31;
  union { bf16 b[8]; u32x4 u; } o;
#pragma unroll
  for (int e = 0; e < 8; ++e) o.b[e] = t[s * 16 + hi * 8 + e][dh * 32 + l31];
  bf16* od = vfr + (((long)(kvh * 64 + kb) * 4 + f) * 64 + l) * 8;
  *reinterpret_cast<u32x4*>(od) = o.u;
}

// ---------- flash attention (causal, GQA), fine split-K, XCD-pinned ----------
// 1280 blocks, NO LDS, NO barriers (waves independent -- the r8 structure).
// kvh = blockIdx%8 pins K/V to one XCD's L2; biggest chunks first.
// Inner loop: 64 keys (pair of 32-key subtiles) per iteration -- two
// independent QK^T MFMA chains, ONE softmax bookkeeping pass, and the NEXT
// pair's K fragments register-prefetched right after the ST MFMAs (their
// latency hides under softmax+PV). V-b issued after the reduce to cap VGPR.
__global__ __launch_bounds__(256)
void flash_attn(const bf16* __restrict__ Q, const bf16* __restrict__ Kfr,
                const bf16* __restrict__ Vfr,
                bf16* __restrict__ po, float* __restrict__ pm, float* __restrict__ pl) {
  const int w = threadIdx.x >> 6, l = threadIdx.x & 63;
  const int lane31 = l & 31, hi = l >> 5;
  const int bb = blockIdx.x;
  const int kvh = bb & 7;               // XCD pin
  const int g = 159 - (bb >> 3);        // 0..159, biggest chunks first

  // invert cumulative chunk id -> (qi, c)
  int qi, c;
  if (g < 16)      { qi = g;                  c = 0; }
  else if (g < 48) { qi = 16 + ((g - 16) >> 1); c = (g - 16) & 1; }
  else if (g < 96) { qi = 32 + (g - 48) / 3;    c = (g - 48) % 3; }
  else             { qi = 48 + ((g - 96) >> 2); c = (g - 96) & 3; }

  const int h = kvh * 4 + w;            // wave -> q-head
  const int s0 = c * 16;
  const int s1 = min(qi + 1, s0 + 16);
  const int pidx = h * 160 + g;         // g == chunk_base(qi) + c

  const int q0 = qi * 32;
  const int q_abs = q0 + lane31;
  const int l8 = l * 8;

  const bf16* kfrh = Kfr + (long)kvh * KVF_HSTRIDE;
  const bf16* vfrh = Vfr + (long)kvh * KVF_HSTRIDE;

  // Q fragments (B-frag of ST): lane -> Q[q0+lane31][cc*16 + hi*8 + e]
  const bf16* qrow = Q + (long)q_abs * DMODEL + h * HDIM + hi * 8;
  bf16x8 qf[4];
#pragma unroll
  for (int cc = 0; cc < 4; ++cc) qf[cc] = *reinterpret_cast<const bf16x8*>(qrow + cc * 16);

  f32x16 o0, o1;
#pragma unroll
  for (int r = 0; r < 16; ++r) { o0[r] = 0.f; o1[r] = 0.f; }
  float m = -3.0e38f, lsum = 0.f;

  // prologue: K fragments for the first PAIR (s0, s0+1) -- always in-bounds
  // (s0 <= 48, so s0+1 <= 49 < 64 key-blocks per head)
  bf16x8 k0, k1, k2, k3, k4, k5, k6, k7;
  {
    const bf16* kp = kfrh + (long)s0 * 2048 + l8;
    k0 = *reinterpret_cast<const bf16x8*>(kp);
    k1 = *reinterpret_cast<const bf16x8*>(kp + 512);
    k2 = *reinterpret_cast<const bf16x8*>(kp + 1024);
    k3 = *reinterpret_cast<const bf16x8*>(kp + 1536);
    k4 = *reinterpret_cast<const bf16x8*>(kp + 2048);
    k5 = *reinterpret_cast<const bf16x8*>(kp + 2560);
    k6 = *reinterpret_cast<const bf16x8*>(kp + 3072);
    k7 = *reinterpret_cast<const bf16x8*>(kp + 3584);
  }

  int sti = s0;
  for (; sti + 1 < s1; sti += 2) {
    const int kb0a = sti * 32, kb0b = kb0a + 32;

    // ---- two independent ST chains over 4 d-chunks (prefetched K) ----
    f32x16 sa, sb;
#pragma unroll
    for (int r = 0; r < 16; ++r) { sa[r] = 0.f; sb[r] = 0.f; }
    sa = __builtin_amdgcn_mfma_f32_32x32x16_bf16(k0, qf[0], sa, 0, 0, 0);
    sb = __builtin_amdgcn_mfma_f32_32x32x16_bf16(k4, qf[0], sb, 0, 0, 0);
    sa = __builtin_amdgcn_mfma_f32_32x32x16_bf16(k1, qf[1], sa, 0, 0, 0);
    sb = __builtin_amdgcn_mfma_f32_32x32x16_bf16(k5, qf[1], sb, 0, 0, 0);
    sa = __builtin_amdgcn_mfma_f32_32x32x16_bf16(k2, qf[2], sa, 0, 0, 0);
    sb = __builtin_amdgcn_mfma_f32_32x32x16_bf16(k6, qf[2], sb, 0, 0, 0);
    sa = __builtin_amdgcn_mfma_f32_32x32x16_bf16(k3, qf[3], sa, 0, 0, 0);
    sb = __builtin_amdgcn_mfma_f32_32x32x16_bf16(k7, qf[3], sb, 0, 0, 0);

    // V subtile a (consumed after softmax)
    const bf16* vp = vfrh + (long)sti * 2048 + l8;
    const bf16x8 va0 = *reinterpret_cast<const bf16x8*>(vp);
    const bf16x8 vb0 = *reinterpret_cast<const bf16x8*>(vp + 512);
    const bf16x8 va1 = *reinterpret_cast<const bf16x8*>(vp + 1024);
    const bf16x8 vb1 = *reinterpret_cast<const bf16x8*>(vp + 1536);

    // NEXT pair's K (clamped, branchless; latency hidden under softmax+PV)
    const long knoff = (sti + 2 < s1) ? (long)(sti + 2) * 2048 : (long)s0 * 2048;
    const bf16* kp = kfrh + knoff + l8;
    const bf16x8 n0 = *reinterpret_cast<const bf16x8*>(kp);
    const bf16x8 n1 = *reinterpret_cast<const bf16x8*>(kp + 512);
    const bf16x8 n2 = *reinterpret_cast<const bf16x8*>(kp + 1024);
    const bf16x8 n3 = *reinterpret_cast<const bf16x8*>(kp + 1536);
    const bf16x8 n4 = *reinterpret_cast<const bf16x8*>(kp + 2048);
    const bf16x8 n5 = *reinterpret_cast<const bf16x8*>(kp + 2560);
    const bf16x8 n6 = *reinterpret_cast<const bf16x8*>(kp + 3072);
    const bf16x8 n7 = *reinterpret_cast<const bf16x8*>(kp + 3584);

    // ---- causal mask (diagonal pair only) ----
    if (kb0b + 31 > q0) {
#pragma unroll
      for (int r = 0; r < 16; ++r) {
        const int krel = (r & 3) + 8 * (r >> 2) + 4 * hi;
        if (kb0a + krel > q_abs) sa[r] = -3.0e38f;
        if (kb0b + krel > q_abs) sb[r] = -3.0e38f;
      }
    }

    // ---- shared online softmax over 64 keys ----
    float t[16];
#pragma unroll
    for (int r = 0; r < 16; ++r) t[r] = fmaxf(sa[r], sb[r]);
#pragma unroll
    for (int s = 8; s > 0; s >>= 1)
#pragma unroll
      for (int r = 0; r < 8; ++r) if (r < s) t[r] = fmaxf(t[r], t[r + s]);
    const float mx = fmaxf(t[0], __shfl_xor(t[0], 32));

    if (!__all(mx - m <= 8.0f)) {        // defer-max, THR=8
      const float mn = fmaxf(m, mx);
      const float al = __builtin_amdgcn_exp2f(m - mn);
      m = mn; lsum *= al;
#pragma unroll
      for (int r = 0; r < 16; ++r) { o0[r] *= al; o1[r] *= al; }
    }
    float rs = 0.f;
#pragma unroll
    for (int r = 0; r < 16; ++r) { sa[r] = __builtin_amdgcn_exp2f(sa[r] - m); rs += sa[r]; }
#pragma unroll
    for (int r = 0; r < 16; ++r) { sb[r] = __builtin_amdgcn_exp2f(sb[r] - m); rs += sb[r]; }
    rs += __shfl_xor(rs, 32);
    lsum += rs;

    // V subtile b issued here (covered by pfrag-a + PV-a; caps VGPR peak)
    const bf16x8 wa0 = *reinterpret_cast<const bf16x8*>(vp + 2048);
    const bf16x8 wb0 = *reinterpret_cast<const bf16x8*>(vp + 2560);
    const bf16x8 wa1 = *reinterpret_cast<const bf16x8*>(vp + 3072);
    const bf16x8 wb1 = *reinterpret_cast<const bf16x8*>(vp + 3584);

    // ---- PV subtile a ----
    {
      const bf16x8 pf0 = make_pfrag(sa[0], sa[1], sa[2], sa[3], sa[4], sa[5], sa[6], sa[7], hi);
      o0 = __builtin_amdgcn_mfma_f32_32x32x16_bf16(va0, pf0, o0, 0, 0, 0);
      o1 = __builtin_amdgcn_mfma_f32_32x32x16_bf16(vb0, pf0, o1, 0, 0, 0);
      const bf16x8 pf1 = make_pfrag(sa[8], sa[9], sa[10], sa[11], sa[12], sa[13], sa[14], sa[15], hi);
      o0 = __builtin_amdgcn_mfma_f32_32x32x16_bf16(va1, pf1, o0, 0, 0, 0);
      o1 = __builtin_amdgcn_mfma_f32_32x32x16_bf16(vb1, pf1, o1, 0, 0, 0);
    }
    // ---- PV subtile b ----
    {
      const bf16x8 pf0 = make_pfrag(sb[0], sb[1], sb[2], sb[3], sb[4], sb[5], sb[6], sb[7], hi);
      o0 = __builtin_amdgcn_mfma_f32_32x32x16_bf16(wa0, pf0, o0, 0, 0, 0);
      o1 = __builtin_amdgcn_mfma_f32_32x32x16_bf16(wb0, pf0, o1, 0, 0, 0);
      const bf16x8 pf1 = make_pfrag(sb[8], sb[9], sb[10], sb[11], sb[12], sb[13], sb[14], sb[15], hi);
      o0 = __builtin_amdgcn_mfma_f32_32x32x16_bf16(wa1, pf1, o0, 0, 0, 0);
      o1 = __builtin_amdgcn_mfma_f32_32x32x16_bf16(wb1, pf1, o1, 0, 0, 0);
    }

    k0 = n0; k1 = n1; k2 = n2; k3 = n3;
    k4 = n4; k5 = n5; k6 = n6; k7 = n7;
  }

  // ---- tail: single 32-key subtile (K already in k0..k3) ----
  if (sti < s1) {
    const int kb0 = sti * 32;
    f32x16 st;
#pragma unroll
    for (int r = 0; r < 16; ++r) st[r] = 0.f;
    st = __builtin_amdgcn_mfma_f32_32x32x16_bf16(k0, qf[0], st, 0, 0, 0);
    st = __builtin_amdgcn_mfma_f32_32x32x16_bf16(k1, qf[1], st, 0, 0, 0);
    st = __builtin_amdgcn_mfma_f32_32x32x16_bf16(k2, qf[2], st, 0, 0, 0);
    st = __builtin_amdgcn_mfma_f32_32x32x16_bf16(k3, qf[3], st, 0, 0, 0);

    const bf16* vp = vfrh + (long)sti * 2048 + l8;
    const bf16x8 va0 = *reinterpret_cast<const bf16x8*>(vp);
    const bf16x8 vb0 = *reinterpret_cast<const bf16x8*>(vp + 512);
    const bf16x8 va1 = *reinterpret_cast<const bf16x8*>(vp + 1024);
    const bf16x8 vb1 = *reinterpret_cast<const bf16x8*>(vp + 1536);

    if (kb0 + 31 > q0) {
#pragma unroll
      for (int r = 0; r < 16; ++r) {
        const int k_abs = kb0 + (r & 3) + 8 * (r >> 2) + 4 * hi;
        if (k_abs > q_abs) st[r] = -3.0e38f;
      }
    }

    float t[8];
#pragma unroll
    for (int r = 0; r < 8; ++r) t[r] = fmaxf(st[r], st[r + 8]);
#pragma unroll
    for (int s = 4; s > 0; s >>= 1)
#pragma unroll
      for (int r = 0; r < 4; ++r) if (r < s) t[r] = fmaxf(t[r], t[r + s]);
    const float mx = fmaxf(t[0], __shfl_xor(t[0], 32));

    if (!__all(mx - m <= 8.0f)) {
      const float mn = fmaxf(m, mx);
      const float al = __builtin_amdgcn_exp2f(m - mn);
      m = mn; lsum *= al;
#pragma unroll
      for (int r = 0; r < 16; ++r) { o0[r] *= al; o1[r] *= al; }
    }
    float rs = 0.f;
#pragma unroll
    for (int r = 0; r < 16; ++r) { st[r] = __builtin_amdgcn_exp2f(st[r] - m); rs += st[r]; }
    rs += __shfl_xor(rs, 32);
    lsum += rs;

    const bf16x8 pf0 = make_pfrag(st[0], st[1], st[2], st[3], st[4], st[5], st[6], st[7], hi);
    o0 = __builtin_amdgcn_mfma_f32_32x32x16_bf16(va0, pf0, o0, 0, 0, 0);
    o1 = __builtin_amdgcn_mfma_f32_32x32x16_bf16(vb0, pf0, o1, 0, 0, 0);
    const bf16x8 pf1 = make_pfrag(st[8], st[9], st[10], st[11], st[12], st[13], st[14], st[15], hi);
    o0 = __builtin_amdgcn_mfma_f32_32x32x16_bf16(va1, pf1, o0, 0, 0, 0);
    o1 = __builtin_amdgcn_mfma_f32_32x32x16_bf16(vb1, pf1, o1, 0, 0, 0);
  }

  // ---- store bf16 partial (unnormalized) + f32 stats ----
  bf16* pbase = po + (long)pidx * 2048 + lane31 * 64;
#pragma unroll
  for (int gg = 0; gg < 4; ++gg) {
    const int d0 = 8 * gg + 4 * hi;
    u32x2 s0v = { pack2(o0[4 * gg + 0], o0[4 * gg + 1]),
                  pack2(o0[4 * gg + 2], o0[4 * gg + 3]) };
    u32x2 s1v = { pack2(o1[4 * gg + 0], o1[4 * gg + 1]),
                  pack2(o1[4 * gg + 2], o1[4 * gg + 3]) };
    *reinterpret_cast<u32x2*>(pbase + d0) = s0v;
    *reinterpret_cast<u32x2*>(pbase + 32 + d0) = s1v;
  }
  if (hi == 0) {
    pm[pidx * 32 + lane31] = m;
    pl[pidx * 32 + lane31] = lsum;
  }
}

// ---------- combine partials: ao[q] = Σ_c O_c·2^(m_c−M) / Σ_c l_c·2^(m_c−M) ----------
__global__ __launch_bounds__(256)
void combine_split(const bf16* __restrict__ po, const float* __restrict__ pm,
                   const float* __restrict__ pl, bf16* __restrict__ ao) {
  const int t = blockIdx.x * 2 + (threadIdx.x >> 7);
  const int tid7 = threadIdx.x & 127;
  const int r = tid7 >> 2;                 // q row 0..31
  const int dc = (tid7 & 3) * 16;          // d chunk
  const int h = t >> 6, qi = t & 63;
  const int nc = 1 + (qi >> 4);
  const int p0 = h * 160 + chunk_base(qi);

  float mv0 = -3e38f, mv1 = -3e38f, mv2 = -3e38f, mv3 = -3e38f;
  float lv0 = 0.f, lv1 = 0.f, lv2 = 0.f, lv3 = 0.f;
  mv0 = pm[(p0 + 0) * 32 + r];              lv0 = pl[(p0 + 0) * 32 + r];
  if (nc > 1) { mv1 = pm[(p0 + 1) * 32 + r]; lv1 = pl[(p0 + 1) * 32 + r]; }
  if (nc > 2) { mv2 = pm[(p0 + 2) * 32 + r]; lv2 = pl[(p0 + 2) * 32 + r]; }
  if (nc > 3) { mv3 = pm[(p0 + 3) * 32 + r]; lv3 = pl[(p0 + 3) * 32 + r]; }
  const float M = fmaxf(fmaxf(mv0, mv1), fmaxf(mv2, mv3));
  const float w0 = __builtin_amdgcn_exp2f(mv0 - M);
  const float w1 = (nc > 1) ? __builtin_amdgcn_exp2f(mv1 - M) : 0.f;
  const float w2 = (nc > 2) ? __builtin_amdgcn_exp2f(mv2 - M) : 0.f;
  const float w3 = (nc > 3) ? __builtin_amdgcn_exp2f(mv3 - M) : 0.f;
  const float invL = 1.0f / (lv0 * w0 + lv1 * w1 + lv2 * w2 + lv3 * w3);

  float acc[16];
#pragma unroll
  for (int j = 0; j < 16; ++j) acc[j] = 0.f;

#pragma unroll
  for (int c = 0; c < 4; ++c) {
    if (c < nc) {
      const float fc = ((c == 0) ? w0 : (c == 1) ? w1 : (c == 2) ? w2 : w3) * invL;
      const bf16* src = po + ((long)(p0 + c) * 2048) + r * 64 + dc;
      const bf16x8 a0 = *reinterpret_cast<const bf16x8*>(src);
      const bf16x8 a1 = *reinterpret_cast<const bf16x8*>(src + 8);
#pragma unroll
      for (int j = 0; j < 8; ++j) {
        acc[j]     += (float)a0[j] * fc;
        acc[8 + j] += (float)a1[j] * fc;
      }
    }
  }

  const long q_abs = (long)qi * 32 + r;
  bf16* od = ao + q_abs * DMODEL + h * HDIM + dc;
  union { bf16 b[16]; u32x4 u[2]; } o;
#pragma unroll
  for (int j = 0; j < 16; ++j) o.b[j] = (bf16)acc[j];
  *reinterpret_cast<u32x4*>(od) = o.u[0];
  *reinterpret_cast<u32x4*>(od + 8) = o.u[1];
}

// ---------- launch ----------
extern "C" void kernel_launch(void* const* d_in, const int* in_sizes, int n_in,
                              void* d_out, int out_size, void* d_ws, size_t ws_size,
                              hipStream_t stream) {
  const float* x       = (const float*)d_in[0];
  const float* w_qkv   = (const float*)d_in[1];
  const float* w_out   = (const float*)d_in[2];
  const float* q_gamma = (const float*)d_in[3];
  const float* k_gamma = (const float*)d_in[4];
  // d_in[5] = mask (causal tril) — implemented analytically.

  char* ws = (char*)d_ws;
  // Region lifetimes (MB offsets):
  bf16* xb    = (bf16*)(ws);                     //  0..8   x bf16 (dead after gemm1)
  bf16* wqb   = (bf16*)(ws + (8ul  << 20));      //  8..20  w_qkv bf16 (dead after gemm1)
  bf16* wob   = (bf16*)(ws + (20ul << 20));      // 20..28  w_out bf16 (until gemm2)
  bf16* qkvpA = (bf16*)(ws + (28ul << 20));      // 28..40  qkv split-K partial 0
  bf16* qkvpB = (bf16*)(ws + (40ul << 20));      // 40..52  qkv split-K partial 1 (dead after rope/repack)
  bf16* qb    = (bf16*)(ws);                     //  0..8   Q (over dead xb)
  bf16* kfr   = (bf16*)(ws + (8ul  << 20));      //  8..10  K frag order (over dead wqb)
  bf16* vfr   = (bf16*)(ws + (10ul << 20));      // 10..12  V frag order
  bf16* po    = (bf16*)(ws + (28ul << 20));      // 28..48  attn partials (over dead qkvp)
  float* pm   = (float*)(ws + (48ul << 20));     // 48..48.7
  float* pl   = (float*)(ws + (49ul << 20));     // 49..49.7
  bf16* ao    = (bf16*)(ws + (52ul << 20));      // 52..60  attention out
  float* out  = (float*)d_out;

  cvt3_f32_bf16<<<2048, 256, 0, stream>>>(x, w_qkv, w_out, xb, wqb, wob);

  // QKV GEMM split-K=2: 768x2 blocks
  gemm_bt<bf16><<<dim3(QKV_N / 64, L_SEQ / 128, 2), 128, 0, stream>>>(xb, wqb, qkvpA, L_SEQ, QKV_N, DMODEL);

  rope_rms<<<(L_SEQ * 40) / 4, 256, 0, stream>>>(qkvpA, qkvpB, q_gamma, k_gamma, qb, kfr);
  repack_v<<<NKVH * (L_SEQ / 32), 256, 0, stream>>>(qkvpA, qkvpB, vfr);

  flash_attn<<<1280, 256, 0, stream>>>(qb, kfr, vfr, po, pm, pl);
  combine_split<<<1024, 256, 0, stream>>>(po, pm, pl, ao);

  gemm_bt<float><<<dim3(DMODEL / 64, L_SEQ / 128, 1), 128, 0, stream>>>(ao, wob, out, L_SEQ, DMODEL, DMODEL);
}